// Round 2
// baseline (140.736 us; speedup 1.0000x reference)
//
#include <hip/hip_runtime.h>
#include <hip/hip_bf16.h>
#include <cstdint>
#include <cstddef>

#define TOK 32768      // B*L
#define CCH 128        // H*NB channels (also DH)
#define DIN 1024       // D

typedef __attribute__((ext_vector_type(8))) short short8;
typedef __attribute__((ext_vector_type(4))) float f32x4;

#define LIST_CAP 262144u

static __device__ __forceinline__ uint16_t f2bf(float f) {
  __hip_bfloat16 h = __float2bfloat16(f);
  return __builtin_bit_cast(uint16_t, h);
}
static __device__ __forceinline__ float bf2f(uint16_t u) {
  __hip_bfloat16 h = __builtin_bit_cast(__hip_bfloat16, u);
  return __bfloat162float(h);
}
// split f32 into hi+lo bf16 (x ~= hi+lo, error ~2^-18 |x|)
static __device__ __forceinline__ void splitbf(float x, uint16_t& hi, uint16_t& lo) {
  hi = f2bf(x);
  lo = f2bf(x - bf2f(hi));
}

// ---------------- prep: pack weights ----------------
// W1r / W1m_hi / W1m_lo : B-fragment layout [16 kt][2 c][8 nt][64 lane][8 j] bf16
//   (k = kt*64 + c*32 + (lane>>4)*8 + j ; n = nt*16 + (lane&15))
// W2r / W2m_hi / W2m_lo : [8 t][4 c][64 lane][8 j] bf16 (B-fragment layout, mfma_16x16x32)
__global__ void prep_kernel(const float* __restrict__ r_w1, const float* __restrict__ r_w2,
                            const float* __restrict__ m_w1, const float* __restrict__ m_w2,
                            const float* __restrict__ logQ, const float* __restrict__ logRavg,
                            uint16_t* __restrict__ W1r, uint16_t* __restrict__ W2r,
                            uint16_t* __restrict__ W1mh, uint16_t* __restrict__ W1ml,
                            uint16_t* __restrict__ W2mh, uint16_t* __restrict__ W2ml,
                            float* __restrict__ PiArr, unsigned int* __restrict__ cnt)
{
  int idx = blockIdx.x * 256 + threadIdx.x;
  if (idx == 0) cnt[0] = 0;
  if (idx < 131072) {
    int e = idx;
    int j = e & 7, lane = (e >> 3) & 63, nt = (e >> 9) & 7, c = (e >> 12) & 1, kt = e >> 13;
    int k = kt * 64 + c * 32 + (lane >> 4) * 8 + j;
    int n = nt * 16 + (lane & 15);
    W1r[e] = f2bf(r_w1[k * 128 + n]);
  } else if (idx < 147456) {
    int e = idx - 131072;
    int j = e & 7, l = (e >> 3) & 63, c = (e >> 9) & 3, t = e >> 11;
    int k = c * 32 + (l >> 4) * 8 + j;
    int col = t * 16 + (l & 15);
    W2r[e] = f2bf(r_w2[k * 128 + col]);
  } else if (idx < 278528) {
    int e = idx - 147456;
    int j = e & 7, lane = (e >> 3) & 63, nt = (e >> 9) & 7, c = (e >> 12) & 1, kt = e >> 13;
    int k = kt * 64 + c * 32 + (lane >> 4) * 8 + j;
    int n = nt * 16 + (lane & 15);
    uint16_t h, l;
    splitbf(m_w1[k * 128 + n], h, l);
    W1mh[e] = h; W1ml[e] = l;
  } else if (idx < 294912) {
    int e = idx - 278528;
    int j = e & 7, l = (e >> 3) & 63, c = (e >> 9) & 3, t = e >> 11;
    int k = c * 32 + (l >> 4) * 8 + j;
    int col = t * 16 + (l & 15);
    uint16_t h, lo;
    splitbf(m_w2[k * 128 + col], h, lo);
    W2mh[e] = h; W2ml[e] = lo;
  } else if (idx < 295040) {
    int i = idx - 294912;
    float Q = expf(logQ[i]);
    float Rv = expf(logRavg[i]);
    PiArr[i] = 0.5f * (-Q + sqrtf(Q * Q + 4.0f * Q * Rv));
  }
}

// ---------------- fused_all: r-MLP (bf16 MFMA) + m-MLP (split-bf16 MFMA) + chunk aggregates ----------------
// R2 structural changes:
//  * 1024 threads (16 waves) per block, wave grid 4 tm x 4 tn, mm removed.
//    2 blocks/CU x 1024 thr = 2048 thr/CU = 100% thread capacity (8 waves/SIMD).
//    __launch_bounds__(1024, 8) -> 64-VGPR cap (accs now only 16 VGPRs).
//  * Epilogue m: nu computed as the 2*pi wrap (wr) directly -- identical to
//    atan2f(sinf,cosf) to ~1e-6 except within 3e-4 of the +-pi boundary, which
//    is exactly the flagged set refine_nu recomputes exactly. Drops sin/cos/atan2.
//  * T14 async-stage split and W1-fragment hoist retained from R1.
__global__ __launch_bounds__(1024, 8) void fused_all(
    const float* __restrict__ X, const float* __restrict__ theta,
    const uint16_t* __restrict__ W1r, const uint16_t* __restrict__ W2r,
    const uint16_t* __restrict__ W1h, const uint16_t* __restrict__ W1l,
    const uint16_t* __restrict__ W2h, const uint16_t* __restrict__ W2l,
    const float* __restrict__ rB1, const float* __restrict__ rB2,
    const float* __restrict__ B1, const float* __restrict__ B2,
    const float* __restrict__ PiArr,
    float* __restrict__ out0, float* __restrict__ out1,
    float* __restrict__ out2, float* __restrict__ out3,
    float* __restrict__ AggA, float* __restrict__ AggU,
    unsigned int* __restrict__ cnt, unsigned int* __restrict__ list)
{
  union SM {
    struct { uint16_t Xh[2][64][72]; uint16_t Xl[2][64][72]; } s1;     // 36864 B
    struct { uint16_t Hh[64][136]; uint16_t Hl[64][136]; uint16_t Hr[64][136]; } s2; // 52224 B
    struct { float2 Agg[4][4][128]; } s3;   // 16384 B
  };
  __shared__ SM sm;

  const int tid = threadIdx.x;
  const int w = tid >> 6, lane = tid & 63;
  const int l15 = lane & 15, l4 = lane >> 4;
  const int tm = w >> 2, tn = w & 3;      // token-group (4) x channel-group (4)
  const int tok0 = blockIdx.x * 64;

  f32x4 accm[2], accr[2];
#pragma unroll
  for (int t = 0; t < 2; ++t) { accm[t] = 0.0f; accr[t] = 0.0f; }

  const int rr = tid >> 4, cc = tid & 15;   // 64 row-slots x 16 col-chunks
  float4 xv0;

  auto stageLoad = [&](int kt) {
    xv0 = *reinterpret_cast<const float4*>(
        X + (size_t)(tok0 + rr) * DIN + kt * 64 + cc * 4);
  };
  auto stageWrite = [&](int b) {
    ushort4 vh, vl;
    splitbf(xv0.x, vh.x, vl.x);
    splitbf(xv0.y, vh.y, vl.y);
    splitbf(xv0.z, vh.z, vl.z);
    splitbf(xv0.w, vh.w, vl.w);
    *reinterpret_cast<ushort4*>(&sm.s1.Xh[b][rr][cc * 4]) = vh;
    *reinterpret_cast<ushort4*>(&sm.s1.Xl[b][rr][cc * 4]) = vl;
  };

  stageLoad(0);
  stageWrite(0);
  __syncthreads();

  for (int kt = 0; kt < 16; ++kt) {
    const int cur = kt & 1;
    if (kt < 15) stageLoad(kt + 1);   // issue early; consumed after MFMA cluster

    // hoist W1 B-fragments for both c-steps
    short8 bh[2][2], bl[2][2], br[2][2];
#pragma unroll
    for (int c = 0; c < 2; ++c)
#pragma unroll
      for (int t = 0; t < 2; ++t) {
        const size_t boff = (size_t)((((kt * 2 + c) * 8 + (tn * 2 + t)) * 64 + lane) * 8);
        bh[c][t] = *reinterpret_cast<const short8*>(W1h + boff);
        bl[c][t] = *reinterpret_cast<const short8*>(W1l + boff);
        br[c][t] = *reinterpret_cast<const short8*>(W1r + boff);
      }

#pragma unroll
    for (int c = 0; c < 2; ++c) {
      const int ko = c * 32 + l4 * 8;
      const int row = tm * 16 + l15;
      short8 ah = *reinterpret_cast<const short8*>(&sm.s1.Xh[cur][row][ko]);
      short8 al = *reinterpret_cast<const short8*>(&sm.s1.Xl[cur][row][ko]);
#pragma unroll
      for (int t = 0; t < 2; ++t) {
        accm[t] = __builtin_amdgcn_mfma_f32_16x16x32_bf16(ah, bh[c][t], accm[t], 0, 0, 0);
        accm[t] = __builtin_amdgcn_mfma_f32_16x16x32_bf16(al, bh[c][t], accm[t], 0, 0, 0);
        accm[t] = __builtin_amdgcn_mfma_f32_16x16x32_bf16(ah, bl[c][t], accm[t], 0, 0, 0);
        accr[t] = __builtin_amdgcn_mfma_f32_16x16x32_bf16(ah, br[c][t], accr[t], 0, 0, 0);
      }
    }

    if (kt < 15) stageWrite(cur ^ 1);   // splitbf + ds_write after compute
    __syncthreads();
  }

  // bias + exact GELU -> H (m: hi/lo split, r: bf16)   [overlays s1 -> barrier above]
#pragma unroll
  for (int t = 0; t < 2; ++t) {
    const int n = (tn * 2 + t) * 16 + l15;
    const float b1m = B1[n];
    const float b1rr = rB1[n];
#pragma unroll
    for (int r = 0; r < 4; ++r) {
      const int row = tm * 16 + l4 * 4 + r;
      const float v = accm[t][r] + b1m;
      const float ev = erff(v / 1.41421356237309515f);
      const float g = 0.5f * v * (ev + 1.0f);
      uint16_t gh, gl;
      splitbf(g, gh, gl);
      sm.s2.Hh[row][n] = gh;
      sm.s2.Hl[row][n] = gl;
      const float vr = accr[t][r] + b1rr;
      const float gr = 0.5f * vr * (1.0f + erff(vr * 0.70710678118654752f));
      sm.s2.Hr[row][n] = f2bf(gr);
    }
  }
  __syncthreads();

  // GEMM2 (K=128): m 3-term split + r single; W2 fragments direct from global
  f32x4 acc2m[2], acc2r[2];
#pragma unroll
  for (int t = 0; t < 2; ++t) { acc2m[t] = 0.0f; acc2r[t] = 0.0f; }

#pragma unroll
  for (int c2 = 0; c2 < 4; ++c2) {
    const int ko = c2 * 32 + l4 * 8;
    const int row = tm * 16 + l15;
    short8 ah = *reinterpret_cast<const short8*>(&sm.s2.Hh[row][ko]);
    short8 al = *reinterpret_cast<const short8*>(&sm.s2.Hl[row][ko]);
    short8 ar = *reinterpret_cast<const short8*>(&sm.s2.Hr[row][ko]);
    short8 b2h[2], b2l[2], b2r[2];
#pragma unroll
    for (int t = 0; t < 2; ++t) {
      const size_t boff = (size_t)((((tn * 2 + t) * 4 + c2) * 64 + lane) * 8);
      b2h[t] = *reinterpret_cast<const short8*>(W2h + boff);
      b2l[t] = *reinterpret_cast<const short8*>(W2l + boff);
      b2r[t] = *reinterpret_cast<const short8*>(W2r + boff);
    }
#pragma unroll
    for (int t = 0; t < 2; ++t) {
      acc2m[t] = __builtin_amdgcn_mfma_f32_16x16x32_bf16(ah, b2h[t], acc2m[t], 0, 0, 0);
      acc2m[t] = __builtin_amdgcn_mfma_f32_16x16x32_bf16(al, b2h[t], acc2m[t], 0, 0, 0);
      acc2m[t] = __builtin_amdgcn_mfma_f32_16x16x32_bf16(ah, b2l[t], acc2m[t], 0, 0, 0);
      acc2r[t] = __builtin_amdgcn_mfma_f32_16x16x32_bf16(ar, b2r[t], acc2r[t], 0, 0, 0);
    }
  }

  // epilogue r: Pi, K, R (overwrite acc2r with K for the aggregate phase)
#pragma unroll
  for (int t = 0; t < 2; ++t) {
    const int n = (tn * 2 + t) * 16 + l15;
    const float b2 = rB2[n];
    const float piv = PiArr[n];
#pragma unroll
    for (int r = 0; r < 4; ++r) {
      const int token = tok0 + tm * 16 + l4 * 4 + r;
      float lr = acc2r[t][r] + b2;
      lr = fminf(fmaxf(lr, -5.0f), 5.0f);
      const float R = expf(lr);
      const float K = piv / fmaxf(piv + R, 1e-8f);
      const size_t off = (size_t)token * CCH + n;
      out1[off] = piv;
      out2[off] = K;
      out3[off] = R;
      acc2r[t][r] = K;
    }
  }

  // epilogue m: nu via direct 2*pi wrap (boundary cases flagged for exact refine)
#pragma unroll
  for (int t = 0; t < 2; ++t) {
    const int n = (tn * 2 + t) * 16 + l15;
    const float b2 = B2[n];
#pragma unroll
    for (int r = 0; r < 4; ++r) {
      const int token = tok0 + tm * 16 + l4 * 4 + r;
      const float mz = acc2m[t][r] + b2;
      const float z = 3.14159265358979323846f * tanhf(mz);
      const float d = z - theta[(size_t)token * CCH + n];
      const float wr = d - 6.2831853071795864769f * rintf(d * 0.15915494309189533577f);
      if (3.14159265358979323846f - fabsf(wr) < 3e-4f) {
        unsigned int p = atomicAdd(cnt, 1u);
        if (p < LIST_CAP) list[p] = (unsigned int)(token * CCH + n);
      }
      out0[(size_t)token * CCH + n] = wr;
      acc2m[t][r] = wr;
    }
  }

  // chunk aggregates: per (ch, tm, l4) 4-token r-chain, then ordered compose
  __syncthreads();   // all H reads done; safe to reuse union as s3
#pragma unroll
  for (int t = 0; t < 2; ++t) {
    const int n = (tn * 2 + t) * 16 + l15;
    float A = 1.0f, U = 0.0f;
#pragma unroll
    for (int r = 0; r < 4; ++r) {
      const float k = acc2r[t][r];
      const float v = acc2m[t][r];
      const float a = 1.0f - k;
      A *= a;
      U = fmaf(a, U, k * v);
    }
    sm.s3.Agg[tm][l4][n] = make_float2(A, U);
  }
  __syncthreads();
  if (tid < 128) {
    const int ch = tid;
    float A = 1.0f, U = 0.0f;
#pragma unroll
    for (int g = 0; g < 16; ++g) {
      const float2 au = sm.s3.Agg[g >> 2][g & 3][ch];
      U = fmaf(au.x, U, au.y);
      A *= au.x;
    }
    AggA[blockIdx.x * CCH + ch] = A;
    AggU[blockIdx.x * CCH + ch] = U;
  }
}

// ---------------- refine_nu: exact f32 sequential-chain recompute of flagged elems ----------------
__global__ __launch_bounds__(128) void refine_nu(
    const float* __restrict__ X, const float* __restrict__ theta,
    const float* __restrict__ W1, const float* __restrict__ B1,
    const float* __restrict__ W2, const float* __restrict__ B2,
    const unsigned int* __restrict__ cnt, const unsigned int* __restrict__ list,
    float* __restrict__ out0)
{
  __shared__ float h[128];
  const int j = threadIdx.x;
  const unsigned int n = min(cnt[0], LIST_CAP);
  for (unsigned int e = blockIdx.x; e < n; e += gridDim.x) {
    const unsigned int idx = list[e];
    const int tok = (int)(idx >> 7), ch = (int)(idx & 127);
    const float* xr = X + (size_t)tok * DIN;
    float acc = 0.0f;
    for (int k = 0; k < DIN; ++k)
      acc = fmaf(xr[k], W1[(size_t)k * CCH + j], acc);
    const float v = acc + B1[j];
    const float ev = erff(v / 1.41421356237309515f);
    h[j] = 0.5f * v * (ev + 1.0f);
    __syncthreads();
    if (j == 0) {
      float a2 = 0.0f;
      for (int k = 0; k < CCH; ++k)
        a2 = fmaf(h[k], W2[(size_t)k * CCH + ch], a2);
      const float mz = a2 + B2[ch];
      const float z = 3.14159265358979323846f * tanhf(mz);
      const float d = z - theta[(size_t)tok * CCH + ch];
      out0[(size_t)tok * CCH + ch] = atan2f(sinf(d), cosf(d));
    }
    __syncthreads();
  }
}

// ---------------- refine_agg: recompute chunk aggregates touched by refine_nu ----------------
__global__ __launch_bounds__(64) void refine_agg(
    const float* __restrict__ Kk, const float* __restrict__ nu,
    const unsigned int* __restrict__ cnt, const unsigned int* __restrict__ list,
    float* __restrict__ AggA, float* __restrict__ AggU)
{
  __shared__ float av[64], uv[64];
  const int i = threadIdx.x;
  const unsigned int n = min(cnt[0], LIST_CAP);
  for (unsigned int e = blockIdx.x; e < n; e += gridDim.x) {
    const unsigned int idx = list[e];
    const int ch = (int)(idx & 127);
    const int blk = (int)(idx >> 13);          // tok >> 6
    const size_t off = (size_t)(blk * 64 + i) * CCH + ch;
    const float k = Kk[off];
    const float v = nu[off];
    av[i] = 1.0f - k;
    uv[i] = k * v;
    __syncthreads();
    if (i == 0) {
      float A = 1.0f, U = 0.0f;
      for (int g = 0; g < 64; ++g) {
        U = fmaf(av[g], U, uv[g]);
        A *= av[g];
      }
      AggA[blk * CCH + ch] = A;
      AggU[blk * CCH + ch] = U;
    }
    __syncthreads();
  }
}

// ---------------- pass2: wave-parallel affine scan over 64 chunks ----------------
__global__ __launch_bounds__(256) void scan_pass2(
    const float* __restrict__ AggA, const float* __restrict__ AggU,
    float* __restrict__ Carry)
{
  const int wid = blockIdx.x * 4 + (threadIdx.x >> 6);  // 0..1023: (b, ch)
  const int b = wid >> 7, ch = wid & 127;
  const int g = threadIdx.x & 63;                        // chunk index
  const size_t idx = (size_t)(b * 64 + g) * CCH + ch;
  float A = AggA[idx];
  float U = AggU[idx];
#pragma unroll
  for (int s = 1; s < 64; s <<= 1) {
    const float pA = __shfl_up(A, s);
    const float pU = __shfl_up(U, s);
    if (g >= s) {
      U = fmaf(A, pU, U);
      A = A * pA;
    }
  }
  float cU = __shfl_up(U, 1);
  if (g == 0) cU = 0.0f;
  Carry[idx] = cU;
}

// ---------------- pass3: apply (K/nu LDS-staged; serial chain runs from LDS) ----------------
__global__ __launch_bounds__(128) void scan_pass3(
    const float* __restrict__ Kk, const float* __restrict__ theta,
    const float* __restrict__ Carry, float* __restrict__ out0)
{
  __shared__ float kb[64 * CCH];
  __shared__ float vb[64 * CCH];
  const int c = threadIdx.x;
  const int blk = blockIdx.x;
  const size_t base = (size_t)blk * 64 * CCH;
  // parallel stage: 8192 floats per array = 2048 float4; 128 threads x 16 each
#pragma unroll
  for (int i = 0; i < 16; ++i) {
    const int e = i * 128 + c;
    reinterpret_cast<float4*>(kb)[e] = reinterpret_cast<const float4*>(Kk + base)[e];
    reinterpret_cast<float4*>(vb)[e] = reinterpret_cast<const float4*>(out0 + base)[e];
  }
  __syncthreads();
  float d = Carry[blk * CCH + c];
#pragma unroll 8
  for (int i = 0; i < 64; ++i) {
    const float k = kb[i * CCH + c];
    const float v = vb[i * CCH + c];
    d = fmaf(1.0f - k, d, k * v);
    const size_t off = base + (size_t)i * CCH + c;
    out0[off] = theta[off] + d;
  }
}

extern "C" void kernel_launch(void* const* d_in, const int* in_sizes, int n_in,
                              void* d_out, int out_size, void* d_ws, size_t ws_size,
                              hipStream_t stream) {
  const float* theta   = (const float*)d_in[0];
  const float* X       = (const float*)d_in[1];
  const float* logQ    = (const float*)d_in[2];
  const float* logRavg = (const float*)d_in[3];
  const float* r_w1    = (const float*)d_in[4];
  const float* r_b1    = (const float*)d_in[5];
  const float* r_w2    = (const float*)d_in[6];
  const float* r_b2    = (const float*)d_in[7];
  const float* m_w1    = (const float*)d_in[8];
  const float* m_b1    = (const float*)d_in[9];
  const float* m_w2    = (const float*)d_in[10];
  const float* m_b2    = (const float*)d_in[11];

  float* out0 = (float*)d_out;             // theta + d (nu scratch first)
  float* out1 = out0 + 4194304;            // Pi
  float* out2 = out0 + 2 * 4194304;        // K
  float* out3 = out0 + 3 * 4194304;        // R

  char* ws = (char*)d_ws;
  uint16_t* W1r  = (uint16_t*)(ws);                  // 262144 B
  uint16_t* W2r  = (uint16_t*)(ws + 262144);         // 32768 B
  float* PiArr   = (float*)(ws + 295936);            // 512 B
  float* AggA    = (float*)(ws + 296448);            // 262144 B
  float* AggU    = (float*)(ws + 558592);            // 262144 B
  float* Carry   = (float*)(ws + 820736);            // 262144 B
  unsigned int* cnt  = (unsigned int*)(ws + 1082880);   // 256 B slot
  unsigned int* list = (unsigned int*)(ws + 1083136);   // 1048576 B
  uint16_t* W1mh = (uint16_t*)(ws + 2131712);        // 262144 B
  uint16_t* W1ml = (uint16_t*)(ws + 2393856);        // 262144 B
  uint16_t* W2mh = (uint16_t*)(ws + 2656000);        // 32768 B
  uint16_t* W2ml = (uint16_t*)(ws + 2688768);        // 32768 B

  prep_kernel<<<1153, 256, 0, stream>>>(r_w1, r_w2, m_w1, m_w2, logQ, logRavg,
                                        W1r, W2r, W1mh, W1ml, W2mh, W2ml,
                                        PiArr, cnt);
  fused_all<<<512, 1024, 0, stream>>>(X, theta, W1r, W2r, W1mh, W1ml, W2mh, W2ml,
                                      r_b1, r_b2, m_b1, m_b2, PiArr,
                                      out0, out1, out2, out3, AggA, AggU, cnt, list);
  refine_nu<<<1024, 128, 0, stream>>>(X, theta, m_w1, m_b1, m_w2, m_b2,
                                      cnt, list, out0);
  refine_agg<<<1024, 64, 0, stream>>>(out2, out0, cnt, list, AggA, AggU);
  scan_pass2<<<256, 256, 0, stream>>>(AggA, AggU, Carry);
  scan_pass3<<<512, 128, 0, stream>>>(out2, theta, Carry, out0);
}

// Round 3
// 123.396 us; speedup vs baseline: 1.1405x; 1.1405x over previous
//
#include <hip/hip_runtime.h>
#include <hip/hip_bf16.h>
#include <cstdint>
#include <cstddef>

#define TOK 32768      // B*L
#define CCH 128        // H*NB channels (also DH)
#define DIN 1024       // D

typedef __attribute__((ext_vector_type(8))) short short8;
typedef __attribute__((ext_vector_type(4))) float f32x4;

#define LIST_CAP 262144u

static __device__ __forceinline__ uint16_t f2bf(float f) {
  __hip_bfloat16 h = __float2bfloat16(f);
  return __builtin_bit_cast(uint16_t, h);
}
static __device__ __forceinline__ float bf2f(uint16_t u) {
  __hip_bfloat16 h = __builtin_bit_cast(__hip_bfloat16, u);
  return __bfloat162float(h);
}
// split f32 into hi+lo bf16 (x ~= hi+lo, error ~2^-18 |x|)
static __device__ __forceinline__ void splitbf(float x, uint16_t& hi, uint16_t& lo) {
  hi = f2bf(x);
  lo = f2bf(x - bf2f(hi));
}

// ---------------- prep: pack weights ----------------
// W1r / W1m_hi / W1m_lo : B-fragment layout [16 kt][2 c][8 nt][64 lane][8 j] bf16
//   (k = kt*64 + c*32 + (lane>>4)*8 + j ; n = nt*16 + (lane&15))
// W2r / W2m_hi / W2m_lo : [8 t][4 c][64 lane][8 j] bf16 (B-fragment layout, mfma_16x16x32)
__global__ void prep_kernel(const float* __restrict__ r_w1, const float* __restrict__ r_w2,
                            const float* __restrict__ m_w1, const float* __restrict__ m_w2,
                            const float* __restrict__ logQ, const float* __restrict__ logRavg,
                            uint16_t* __restrict__ W1r, uint16_t* __restrict__ W2r,
                            uint16_t* __restrict__ W1mh, uint16_t* __restrict__ W1ml,
                            uint16_t* __restrict__ W2mh, uint16_t* __restrict__ W2ml,
                            float* __restrict__ PiArr, unsigned int* __restrict__ cnt)
{
  int idx = blockIdx.x * 256 + threadIdx.x;
  if (idx == 0) cnt[0] = 0;
  if (idx < 131072) {
    int e = idx;
    int j = e & 7, lane = (e >> 3) & 63, nt = (e >> 9) & 7, c = (e >> 12) & 1, kt = e >> 13;
    int k = kt * 64 + c * 32 + (lane >> 4) * 8 + j;
    int n = nt * 16 + (lane & 15);
    W1r[e] = f2bf(r_w1[k * 128 + n]);
  } else if (idx < 147456) {
    int e = idx - 131072;
    int j = e & 7, l = (e >> 3) & 63, c = (e >> 9) & 3, t = e >> 11;
    int k = c * 32 + (l >> 4) * 8 + j;
    int col = t * 16 + (l & 15);
    W2r[e] = f2bf(r_w2[k * 128 + col]);
  } else if (idx < 278528) {
    int e = idx - 147456;
    int j = e & 7, lane = (e >> 3) & 63, nt = (e >> 9) & 7, c = (e >> 12) & 1, kt = e >> 13;
    int k = kt * 64 + c * 32 + (lane >> 4) * 8 + j;
    int n = nt * 16 + (lane & 15);
    uint16_t h, l;
    splitbf(m_w1[k * 128 + n], h, l);
    W1mh[e] = h; W1ml[e] = l;
  } else if (idx < 294912) {
    int e = idx - 278528;
    int j = e & 7, l = (e >> 3) & 63, c = (e >> 9) & 3, t = e >> 11;
    int k = c * 32 + (l >> 4) * 8 + j;
    int col = t * 16 + (l & 15);
    uint16_t h, lo;
    splitbf(m_w2[k * 128 + col], h, lo);
    W2mh[e] = h; W2ml[e] = lo;
  } else if (idx < 295040) {
    int i = idx - 294912;
    float Q = expf(logQ[i]);
    float Rv = expf(logRavg[i]);
    PiArr[i] = 0.5f * (-Q + sqrtf(Q * Q + 4.0f * Q * Rv));
  }
}

// ---------------- fused_all: r-MLP (bf16 MFMA) + m-MLP (split-bf16 MFMA) + chunk aggregates ----------------
// R3 structural changes (math identical to R1/R2):
//  * Back to 512 threads / 8 waves (R2's 1024-thr/64-VGPR-cap starved the
//    scheduler: VGPR=32, all prefetch hoists defeated -> slower despite 78% occ).
//  * Wave remap: tn = w (0..7), mm = 4 -- each wave owns ALL 64 token rows x one
//    16-ch slice. Same 32 MFMA/wave/kt but W1-fragment loads halve (12 -> 6/kt)
//    and 6 fragments (24 VGPRs) actually fit hoisted under the 128-VGPR cap.
//  * 2-deep X prefetch: load(kt+2) issued at top of iter kt, ds_write at end of
//    iter kt+1 -> full-iteration latency window instead of intra-iteration.
//  * W2 fragments (12) prefetched before the GELU VALU phase.
//  * wr-wrap epilogue + LDS-staged scan_pass3 retained from R2.
__global__ __launch_bounds__(512, 4) void fused_all(
    const float* __restrict__ X, const float* __restrict__ theta,
    const uint16_t* __restrict__ W1r, const uint16_t* __restrict__ W2r,
    const uint16_t* __restrict__ W1h, const uint16_t* __restrict__ W1l,
    const uint16_t* __restrict__ W2h, const uint16_t* __restrict__ W2l,
    const float* __restrict__ rB1, const float* __restrict__ rB2,
    const float* __restrict__ B1, const float* __restrict__ B2,
    const float* __restrict__ PiArr,
    float* __restrict__ out0, float* __restrict__ out1,
    float* __restrict__ out2, float* __restrict__ out3,
    float* __restrict__ AggA, float* __restrict__ AggU,
    unsigned int* __restrict__ cnt, unsigned int* __restrict__ list)
{
  union SM {
    struct { uint16_t Xh[2][64][72]; uint16_t Xl[2][64][72]; } s1;     // 36864 B
    struct { uint16_t Hh[64][136]; uint16_t Hl[64][136]; uint16_t Hr[64][136]; } s2; // 52224 B
    struct { float2 Agg[4][4][128]; } s3;   // 16384 B
  };
  __shared__ SM sm;

  const int tid = threadIdx.x;
  const int w = tid >> 6, lane = tid & 63;
  const int l15 = lane & 15, l4 = lane >> 4;
  const int tn = w;                  // channel-slice 0..7 (16 channels each)
  const int tok0 = blockIdx.x * 64;

  f32x4 accm[4], accr[4];
#pragma unroll
  for (int m = 0; m < 4; ++m) { accm[m] = 0.0f; accr[m] = 0.0f; }

  const int rr = tid >> 4, cc = tid & 15;   // 32 row-slots x 16 col-chunks (x2 rows/thread)
  float4 xa0, xa1, xb0, xb1;

  auto ldX = [&](int kt, float4& v0, float4& v1) {
    v0 = *reinterpret_cast<const float4*>(
        X + (size_t)(tok0 + rr) * DIN + kt * 64 + cc * 4);
    v1 = *reinterpret_cast<const float4*>(
        X + (size_t)(tok0 + rr + 32) * DIN + kt * 64 + cc * 4);
  };
  auto wrX = [&](int b, const float4& v0, const float4& v1) {
    ushort4 vh, vl;
    splitbf(v0.x, vh.x, vl.x);
    splitbf(v0.y, vh.y, vl.y);
    splitbf(v0.z, vh.z, vl.z);
    splitbf(v0.w, vh.w, vl.w);
    *reinterpret_cast<ushort4*>(&sm.s1.Xh[b][rr][cc * 4]) = vh;
    *reinterpret_cast<ushort4*>(&sm.s1.Xl[b][rr][cc * 4]) = vl;
    splitbf(v1.x, vh.x, vl.x);
    splitbf(v1.y, vh.y, vl.y);
    splitbf(v1.z, vh.z, vl.z);
    splitbf(v1.w, vh.w, vl.w);
    *reinterpret_cast<ushort4*>(&sm.s1.Xh[b][rr + 32][cc * 4]) = vh;
    *reinterpret_cast<ushort4*>(&sm.s1.Xl[b][rr + 32][cc * 4]) = vl;
  };

  // pipeline prologue: buf0 <- kt0; xa holds kt1 (written at end of iter 0)
  ldX(0, xa0, xa1);
  wrX(0, xa0, xa1);
  ldX(1, xa0, xa1);
  __syncthreads();

#pragma unroll
  for (int kt = 0; kt < 16; ++kt) {
    const int cur = kt & 1;

    // hoist all 6 W1 B-fragments for this kt (fits: 24 VGPRs)
    short8 bh[2], bl[2], br[2];
#pragma unroll
    for (int c = 0; c < 2; ++c) {
      const size_t boff = (size_t)((((kt * 2 + c) * 8 + tn) * 64 + lane) * 8);
      bh[c] = *reinterpret_cast<const short8*>(W1h + boff);
      bl[c] = *reinterpret_cast<const short8*>(W1l + boff);
      br[c] = *reinterpret_cast<const short8*>(W1r + boff);
    }
    if (kt < 14) ldX(kt + 2, xb0, xb1);   // 2-deep X prefetch

#pragma unroll
    for (int c = 0; c < 2; ++c) {
      const int ko = c * 32 + l4 * 8;
#pragma unroll
      for (int m = 0; m < 4; ++m) {
        const int row = m * 16 + l15;
        const short8 ah = *reinterpret_cast<const short8*>(&sm.s1.Xh[cur][row][ko]);
        const short8 al = *reinterpret_cast<const short8*>(&sm.s1.Xl[cur][row][ko]);
        accm[m] = __builtin_amdgcn_mfma_f32_16x16x32_bf16(ah, bh[c], accm[m], 0, 0, 0);
        accm[m] = __builtin_amdgcn_mfma_f32_16x16x32_bf16(al, bh[c], accm[m], 0, 0, 0);
        accm[m] = __builtin_amdgcn_mfma_f32_16x16x32_bf16(ah, bl[c], accm[m], 0, 0, 0);
        accr[m] = __builtin_amdgcn_mfma_f32_16x16x32_bf16(ah, br[c], accr[m], 0, 0, 0);
      }
    }

    if (kt < 15) { wrX(cur ^ 1, xa0, xa1); xa0 = xb0; xa1 = xb1; }
    __syncthreads();
  }

  // prefetch all 12 W2 B-fragments; they land during the GELU VALU phase
  short8 b2h[4], b2l[4], b2r[4];
#pragma unroll
  for (int c2 = 0; c2 < 4; ++c2) {
    const size_t boff = (size_t)(((tn * 4 + c2) * 64 + lane) * 8);
    b2h[c2] = *reinterpret_cast<const short8*>(W2h + boff);
    b2l[c2] = *reinterpret_cast<const short8*>(W2l + boff);
    b2r[c2] = *reinterpret_cast<const short8*>(W2r + boff);
  }

  // bias + exact GELU -> H (m: hi/lo split, r: bf16)   [overlays s1 -> barrier above]
  const int n = tn * 16 + l15;
  {
    const float b1m = B1[n];
    const float b1rr = rB1[n];
#pragma unroll
    for (int m = 0; m < 4; ++m)
#pragma unroll
      for (int r = 0; r < 4; ++r) {
        const int row = m * 16 + l4 * 4 + r;
        const float v = accm[m][r] + b1m;
        const float ev = erff(v / 1.41421356237309515f);
        const float g = 0.5f * v * (ev + 1.0f);
        uint16_t gh, gl;
        splitbf(g, gh, gl);
        sm.s2.Hh[row][n] = gh;
        sm.s2.Hl[row][n] = gl;
        const float vr = accr[m][r] + b1rr;
        const float gr = 0.5f * vr * (1.0f + erff(vr * 0.70710678118654752f));
        sm.s2.Hr[row][n] = f2bf(gr);
      }
  }
  __syncthreads();

  // GEMM2 (K=128): m 3-term split + r single; W2 fragments already in regs
  f32x4 acc2m[4], acc2r[4];
#pragma unroll
  for (int m = 0; m < 4; ++m) { acc2m[m] = 0.0f; acc2r[m] = 0.0f; }

#pragma unroll
  for (int c2 = 0; c2 < 4; ++c2) {
    const int ko = c2 * 32 + l4 * 8;
#pragma unroll
    for (int m = 0; m < 4; ++m) {
      const int row = m * 16 + l15;
      const short8 ah = *reinterpret_cast<const short8*>(&sm.s2.Hh[row][ko]);
      const short8 al = *reinterpret_cast<const short8*>(&sm.s2.Hl[row][ko]);
      const short8 ar = *reinterpret_cast<const short8*>(&sm.s2.Hr[row][ko]);
      acc2m[m] = __builtin_amdgcn_mfma_f32_16x16x32_bf16(ah, b2h[c2], acc2m[m], 0, 0, 0);
      acc2m[m] = __builtin_amdgcn_mfma_f32_16x16x32_bf16(al, b2h[c2], acc2m[m], 0, 0, 0);
      acc2m[m] = __builtin_amdgcn_mfma_f32_16x16x32_bf16(ah, b2l[c2], acc2m[m], 0, 0, 0);
      acc2r[m] = __builtin_amdgcn_mfma_f32_16x16x32_bf16(ar, b2r[c2], acc2r[m], 0, 0, 0);
    }
  }

  // epilogue r: Pi, K, R (overwrite acc2r with K for the aggregate phase)
  {
    const float b2 = rB2[n];
    const float piv = PiArr[n];
#pragma unroll
    for (int m = 0; m < 4; ++m)
#pragma unroll
      for (int r = 0; r < 4; ++r) {
        const int token = tok0 + m * 16 + l4 * 4 + r;
        float lr = acc2r[m][r] + b2;
        lr = fminf(fmaxf(lr, -5.0f), 5.0f);
        const float R = expf(lr);
        const float K = piv / fmaxf(piv + R, 1e-8f);
        const size_t off = (size_t)token * CCH + n;
        out1[off] = piv;
        out2[off] = K;
        out3[off] = R;
        acc2r[m][r] = K;
      }
  }

  // epilogue m: nu via direct 2*pi wrap (boundary cases flagged for exact refine)
  {
    const float b2 = B2[n];
#pragma unroll
    for (int m = 0; m < 4; ++m)
#pragma unroll
      for (int r = 0; r < 4; ++r) {
        const int token = tok0 + m * 16 + l4 * 4 + r;
        const float mz = acc2m[m][r] + b2;
        const float z = 3.14159265358979323846f * tanhf(mz);
        const float d = z - theta[(size_t)token * CCH + n];
        const float wr = d - 6.2831853071795864769f * rintf(d * 0.15915494309189533577f);
        if (3.14159265358979323846f - fabsf(wr) < 3e-4f) {
          unsigned int p = atomicAdd(cnt, 1u);
          if (p < LIST_CAP) list[p] = (unsigned int)(token * CCH + n);
        }
        out0[(size_t)token * CCH + n] = wr;
        acc2m[m][r] = wr;
      }
  }

  // chunk aggregates: per (ch, m, l4) 4-token r-chain, then ordered compose
  __syncthreads();   // all H reads done; safe to reuse union as s3
#pragma unroll
  for (int m = 0; m < 4; ++m) {
    float A = 1.0f, U = 0.0f;
#pragma unroll
    for (int r = 0; r < 4; ++r) {
      const float k = acc2r[m][r];
      const float v = acc2m[m][r];
      const float a = 1.0f - k;
      A *= a;
      U = fmaf(a, U, k * v);
    }
    sm.s3.Agg[m][l4][n] = make_float2(A, U);
  }
  __syncthreads();
  if (tid < 128) {
    const int ch = tid;
    float A = 1.0f, U = 0.0f;
#pragma unroll
    for (int g = 0; g < 16; ++g) {
      const float2 au = sm.s3.Agg[g >> 2][g & 3][ch];
      U = fmaf(au.x, U, au.y);
      A *= au.x;
    }
    AggA[blockIdx.x * CCH + ch] = A;
    AggU[blockIdx.x * CCH + ch] = U;
  }
}

// ---------------- refine_nu: exact f32 sequential-chain recompute of flagged elems ----------------
__global__ __launch_bounds__(128) void refine_nu(
    const float* __restrict__ X, const float* __restrict__ theta,
    const float* __restrict__ W1, const float* __restrict__ B1,
    const float* __restrict__ W2, const float* __restrict__ B2,
    const unsigned int* __restrict__ cnt, const unsigned int* __restrict__ list,
    float* __restrict__ out0)
{
  __shared__ float h[128];
  const int j = threadIdx.x;
  const unsigned int n = min(cnt[0], LIST_CAP);
  for (unsigned int e = blockIdx.x; e < n; e += gridDim.x) {
    const unsigned int idx = list[e];
    const int tok = (int)(idx >> 7), ch = (int)(idx & 127);
    const float* xr = X + (size_t)tok * DIN;
    float acc = 0.0f;
    for (int k = 0; k < DIN; ++k)
      acc = fmaf(xr[k], W1[(size_t)k * CCH + j], acc);
    const float v = acc + B1[j];
    const float ev = erff(v / 1.41421356237309515f);
    h[j] = 0.5f * v * (ev + 1.0f);
    __syncthreads();
    if (j == 0) {
      float a2 = 0.0f;
      for (int k = 0; k < CCH; ++k)
        a2 = fmaf(h[k], W2[(size_t)k * CCH + ch], a2);
      const float mz = a2 + B2[ch];
      const float z = 3.14159265358979323846f * tanhf(mz);
      const float d = z - theta[(size_t)tok * CCH + ch];
      out0[(size_t)tok * CCH + ch] = atan2f(sinf(d), cosf(d));
    }
    __syncthreads();
  }
}

// ---------------- refine_agg: recompute chunk aggregates touched by refine_nu ----------------
__global__ __launch_bounds__(64) void refine_agg(
    const float* __restrict__ Kk, const float* __restrict__ nu,
    const unsigned int* __restrict__ cnt, const unsigned int* __restrict__ list,
    float* __restrict__ AggA, float* __restrict__ AggU)
{
  __shared__ float av[64], uv[64];
  const int i = threadIdx.x;
  const unsigned int n = min(cnt[0], LIST_CAP);
  for (unsigned int e = blockIdx.x; e < n; e += gridDim.x) {
    const unsigned int idx = list[e];
    const int ch = (int)(idx & 127);
    const int blk = (int)(idx >> 13);          // tok >> 6
    const size_t off = (size_t)(blk * 64 + i) * CCH + ch;
    const float k = Kk[off];
    const float v = nu[off];
    av[i] = 1.0f - k;
    uv[i] = k * v;
    __syncthreads();
    if (i == 0) {
      float A = 1.0f, U = 0.0f;
      for (int g = 0; g < 64; ++g) {
        U = fmaf(av[g], U, uv[g]);
        A *= av[g];
      }
      AggA[blk * CCH + ch] = A;
      AggU[blk * CCH + ch] = U;
    }
    __syncthreads();
  }
}

// ---------------- pass2: wave-parallel affine scan over 64 chunks ----------------
__global__ __launch_bounds__(256) void scan_pass2(
    const float* __restrict__ AggA, const float* __restrict__ AggU,
    float* __restrict__ Carry)
{
  const int wid = blockIdx.x * 4 + (threadIdx.x >> 6);  // 0..1023: (b, ch)
  const int b = wid >> 7, ch = wid & 127;
  const int g = threadIdx.x & 63;                        // chunk index
  const size_t idx = (size_t)(b * 64 + g) * CCH + ch;
  float A = AggA[idx];
  float U = AggU[idx];
#pragma unroll
  for (int s = 1; s < 64; s <<= 1) {
    const float pA = __shfl_up(A, s);
    const float pU = __shfl_up(U, s);
    if (g >= s) {
      U = fmaf(A, pU, U);
      A = A * pA;
    }
  }
  float cU = __shfl_up(U, 1);
  if (g == 0) cU = 0.0f;
  Carry[idx] = cU;
}

// ---------------- pass3: apply (K/nu LDS-staged; serial chain runs from LDS) ----------------
__global__ __launch_bounds__(128) void scan_pass3(
    const float* __restrict__ Kk, const float* __restrict__ theta,
    const float* __restrict__ Carry, float* __restrict__ out0)
{
  __shared__ float kb[64 * CCH];
  __shared__ float vb[64 * CCH];
  const int c = threadIdx.x;
  const int blk = blockIdx.x;
  const size_t base = (size_t)blk * 64 * CCH;
  // parallel stage: 8192 floats per array = 2048 float4; 128 threads x 16 each
#pragma unroll
  for (int i = 0; i < 16; ++i) {
    const int e = i * 128 + c;
    reinterpret_cast<float4*>(kb)[e] = reinterpret_cast<const float4*>(Kk + base)[e];
    reinterpret_cast<float4*>(vb)[e] = reinterpret_cast<const float4*>(out0 + base)[e];
  }
  __syncthreads();
  float d = Carry[blk * CCH + c];
#pragma unroll 8
  for (int i = 0; i < 64; ++i) {
    const float k = kb[i * CCH + c];
    const float v = vb[i * CCH + c];
    d = fmaf(1.0f - k, d, k * v);
    const size_t off = base + (size_t)i * CCH + c;
    out0[off] = theta[off] + d;
  }
}

extern "C" void kernel_launch(void* const* d_in, const int* in_sizes, int n_in,
                              void* d_out, int out_size, void* d_ws, size_t ws_size,
                              hipStream_t stream) {
  const float* theta   = (const float*)d_in[0];
  const float* X       = (const float*)d_in[1];
  const float* logQ    = (const float*)d_in[2];
  const float* logRavg = (const float*)d_in[3];
  const float* r_w1    = (const float*)d_in[4];
  const float* r_b1    = (const float*)d_in[5];
  const float* r_w2    = (const float*)d_in[6];
  const float* r_b2    = (const float*)d_in[7];
  const float* m_w1    = (const float*)d_in[8];
  const float* m_b1    = (const float*)d_in[9];
  const float* m_w2    = (const float*)d_in[10];
  const float* m_b2    = (const float*)d_in[11];

  float* out0 = (float*)d_out;             // theta + d (nu scratch first)
  float* out1 = out0 + 4194304;            // Pi
  float* out2 = out0 + 2 * 4194304;        // K
  float* out3 = out0 + 3 * 4194304;        // R

  char* ws = (char*)d_ws;
  uint16_t* W1r  = (uint16_t*)(ws);                  // 262144 B
  uint16_t* W2r  = (uint16_t*)(ws + 262144);         // 32768 B
  float* PiArr   = (float*)(ws + 295936);            // 512 B
  float* AggA    = (float*)(ws + 296448);            // 262144 B
  float* AggU    = (float*)(ws + 558592);            // 262144 B
  float* Carry   = (float*)(ws + 820736);            // 262144 B
  unsigned int* cnt  = (unsigned int*)(ws + 1082880);   // 256 B slot
  unsigned int* list = (unsigned int*)(ws + 1083136);   // 1048576 B
  uint16_t* W1mh = (uint16_t*)(ws + 2131712);        // 262144 B
  uint16_t* W1ml = (uint16_t*)(ws + 2393856);        // 262144 B
  uint16_t* W2mh = (uint16_t*)(ws + 2656000);        // 32768 B
  uint16_t* W2ml = (uint16_t*)(ws + 2688768);        // 32768 B

  prep_kernel<<<1153, 256, 0, stream>>>(r_w1, r_w2, m_w1, m_w2, logQ, logRavg,
                                        W1r, W2r, W1mh, W1ml, W2mh, W2ml,
                                        PiArr, cnt);
  fused_all<<<512, 512, 0, stream>>>(X, theta, W1r, W2r, W1mh, W1ml, W2mh, W2ml,
                                     r_b1, r_b2, m_b1, m_b2, PiArr,
                                     out0, out1, out2, out3, AggA, AggU, cnt, list);
  refine_nu<<<1024, 128, 0, stream>>>(X, theta, m_w1, m_b1, m_w2, m_b2,
                                      cnt, list, out0);
  refine_agg<<<1024, 64, 0, stream>>>(out2, out0, cnt, list, AggA, AggU);
  scan_pass2<<<256, 256, 0, stream>>>(AggA, AggU, Carry);
  scan_pass3<<<512, 128, 0, stream>>>(out2, theta, Carry, out0);
}

// Round 4
// 122.475 us; speedup vs baseline: 1.1491x; 1.0075x over previous
//
#include <hip/hip_runtime.h>
#include <hip/hip_bf16.h>
#include <cstdint>
#include <cstddef>

#define TOK 32768      // B*L
#define CCH 128        // H*NB channels (also DH)
#define DIN 1024       // D

typedef __attribute__((ext_vector_type(8))) short short8;
typedef __attribute__((ext_vector_type(4))) float f32x4;

#define LIST_CAP 262144u

static __device__ __forceinline__ uint16_t f2bf(float f) {
  __hip_bfloat16 h = __float2bfloat16(f);
  return __builtin_bit_cast(uint16_t, h);
}
static __device__ __forceinline__ float bf2f(uint16_t u) {
  __hip_bfloat16 h = __builtin_bit_cast(__hip_bfloat16, u);
  return __bfloat162float(h);
}
// split f32 into hi+lo bf16 (x ~= hi+lo, error ~2^-18 |x|)
static __device__ __forceinline__ void splitbf(float x, uint16_t& hi, uint16_t& lo) {
  hi = f2bf(x);
  lo = f2bf(x - bf2f(hi));
}

// ---------------- prep: pack weights ----------------
// W1r / W1m_hi / W1m_lo : B-fragment layout [16 kt][2 c][8 nt][64 lane][8 j] bf16
//   (k = kt*64 + c*32 + (lane>>4)*8 + j ; n = nt*16 + (lane&15))
// W2r / W2m_hi / W2m_lo : [8 t][4 c][64 lane][8 j] bf16 (B-fragment layout, mfma_16x16x32)
__global__ void prep_kernel(const float* __restrict__ r_w1, const float* __restrict__ r_w2,
                            const float* __restrict__ m_w1, const float* __restrict__ m_w2,
                            const float* __restrict__ logQ, const float* __restrict__ logRavg,
                            uint16_t* __restrict__ W1r, uint16_t* __restrict__ W2r,
                            uint16_t* __restrict__ W1mh, uint16_t* __restrict__ W1ml,
                            uint16_t* __restrict__ W2mh, uint16_t* __restrict__ W2ml,
                            float* __restrict__ PiArr, unsigned int* __restrict__ cnt)
{
  int idx = blockIdx.x * 256 + threadIdx.x;
  if (idx == 0) cnt[0] = 0;
  if (idx < 131072) {
    int e = idx;
    int j = e & 7, lane = (e >> 3) & 63, nt = (e >> 9) & 7, c = (e >> 12) & 1, kt = e >> 13;
    int k = kt * 64 + c * 32 + (lane >> 4) * 8 + j;
    int n = nt * 16 + (lane & 15);
    W1r[e] = f2bf(r_w1[k * 128 + n]);
  } else if (idx < 147456) {
    int e = idx - 131072;
    int j = e & 7, l = (e >> 3) & 63, c = (e >> 9) & 3, t = e >> 11;
    int k = c * 32 + (l >> 4) * 8 + j;
    int col = t * 16 + (l & 15);
    W2r[e] = f2bf(r_w2[k * 128 + col]);
  } else if (idx < 278528) {
    int e = idx - 147456;
    int j = e & 7, lane = (e >> 3) & 63, nt = (e >> 9) & 7, c = (e >> 12) & 1, kt = e >> 13;
    int k = kt * 64 + c * 32 + (lane >> 4) * 8 + j;
    int n = nt * 16 + (lane & 15);
    uint16_t h, l;
    splitbf(m_w1[k * 128 + n], h, l);
    W1mh[e] = h; W1ml[e] = l;
  } else if (idx < 294912) {
    int e = idx - 278528;
    int j = e & 7, l = (e >> 3) & 63, c = (e >> 9) & 3, t = e >> 11;
    int k = c * 32 + (l >> 4) * 8 + j;
    int col = t * 16 + (l & 15);
    uint16_t h, lo;
    splitbf(m_w2[k * 128 + col], h, lo);
    W2mh[e] = h; W2ml[e] = lo;
  } else if (idx < 295040) {
    int i = idx - 294912;
    float Q = expf(logQ[i]);
    float Rv = expf(logRavg[i]);
    PiArr[i] = 0.5f * (-Q + sqrtf(Q * Q + 4.0f * Q * Rv));
  }
}

// ---------------- fused_all: r-MLP (bf16 MFMA) + m-MLP (split-bf16 MFMA) + chunk aggregates ----------------
// R4 structural change (math identical):
//  * W1 B-fragments register-double-buffered: kt+1's 6 fragments are loaded
//    DURING kt's MFMA cluster (full-iteration L2-latency window). R3 evidence:
//    halving same-iter B-loads beat doubling LDS reads -> B-load latency is the
//    stall; this removes it entirely from the same-iteration critical path.
//  * X prefetch reverted 2-deep -> 1-deep to pay for the extra 24 B-regs under
//    the 128-VGPR cap (X is consumed next-iter; 1-deep window ~ full MFMA cluster).
//  * Everything else identical to R3 (tn=8 wave layout, GEMM2 W2 prefetch,
//    wr-wrap epilogue, LDS-staged scan_pass3).
__global__ __launch_bounds__(512, 4) void fused_all(
    const float* __restrict__ X, const float* __restrict__ theta,
    const uint16_t* __restrict__ W1r, const uint16_t* __restrict__ W2r,
    const uint16_t* __restrict__ W1h, const uint16_t* __restrict__ W1l,
    const uint16_t* __restrict__ W2h, const uint16_t* __restrict__ W2l,
    const float* __restrict__ rB1, const float* __restrict__ rB2,
    const float* __restrict__ B1, const float* __restrict__ B2,
    const float* __restrict__ PiArr,
    float* __restrict__ out0, float* __restrict__ out1,
    float* __restrict__ out2, float* __restrict__ out3,
    float* __restrict__ AggA, float* __restrict__ AggU,
    unsigned int* __restrict__ cnt, unsigned int* __restrict__ list)
{
  union SM {
    struct { uint16_t Xh[2][64][72]; uint16_t Xl[2][64][72]; } s1;     // 36864 B
    struct { uint16_t Hh[64][136]; uint16_t Hl[64][136]; uint16_t Hr[64][136]; } s2; // 52224 B
    struct { float2 Agg[4][4][128]; } s3;   // 16384 B
  };
  __shared__ SM sm;

  const int tid = threadIdx.x;
  const int w = tid >> 6, lane = tid & 63;
  const int l15 = lane & 15, l4 = lane >> 4;
  const int tn = w;                  // channel-slice 0..7 (16 channels each)
  const int tok0 = blockIdx.x * 64;

  f32x4 accm[4], accr[4];
#pragma unroll
  for (int m = 0; m < 4; ++m) { accm[m] = 0.0f; accr[m] = 0.0f; }

  const int rr = tid >> 4, cc = tid & 15;   // 32 row-slots x 16 col-chunks (x2 rows/thread)
  float4 xa0, xa1;

  auto ldX = [&](int kt, float4& v0, float4& v1) {
    v0 = *reinterpret_cast<const float4*>(
        X + (size_t)(tok0 + rr) * DIN + kt * 64 + cc * 4);
    v1 = *reinterpret_cast<const float4*>(
        X + (size_t)(tok0 + rr + 32) * DIN + kt * 64 + cc * 4);
  };
  auto wrX = [&](int b, const float4& v0, const float4& v1) {
    ushort4 vh, vl;
    splitbf(v0.x, vh.x, vl.x);
    splitbf(v0.y, vh.y, vl.y);
    splitbf(v0.z, vh.z, vl.z);
    splitbf(v0.w, vh.w, vl.w);
    *reinterpret_cast<ushort4*>(&sm.s1.Xh[b][rr][cc * 4]) = vh;
    *reinterpret_cast<ushort4*>(&sm.s1.Xl[b][rr][cc * 4]) = vl;
    splitbf(v1.x, vh.x, vl.x);
    splitbf(v1.y, vh.y, vl.y);
    splitbf(v1.z, vh.z, vl.z);
    splitbf(v1.w, vh.w, vl.w);
    *reinterpret_cast<ushort4*>(&sm.s1.Xh[b][rr + 32][cc * 4]) = vh;
    *reinterpret_cast<ushort4*>(&sm.s1.Xl[b][rr + 32][cc * 4]) = vl;
  };
  auto ldB = [&](int kt, short8 (&h)[2], short8 (&l)[2], short8 (&r)[2]) {
#pragma unroll
    for (int c = 0; c < 2; ++c) {
      const size_t boff = (size_t)((((kt * 2 + c) * 8 + tn) * 64 + lane) * 8);
      h[c] = *reinterpret_cast<const short8*>(W1h + boff);
      l[c] = *reinterpret_cast<const short8*>(W1l + boff);
      r[c] = *reinterpret_cast<const short8*>(W1r + boff);
    }
  };

  // pipeline prologue: buf0 <- kt0; B-frags for kt0 loaded into cur regs
  short8 bhc[2], blc[2], brc[2], bhn[2], bln[2], brn[2];
  ldX(0, xa0, xa1);
  wrX(0, xa0, xa1);
  ldB(0, bhc, blc, brc);
  __syncthreads();

#pragma unroll
  for (int kt = 0; kt < 16; ++kt) {
    const int cur = kt & 1;

    if (kt < 15) {
      ldX(kt + 1, xa0, xa1);        // 1-deep X prefetch (consumed next iter)
      ldB(kt + 1, bhn, bln, brn);   // 2-deep B pipeline (consumed next iter)
    }

#pragma unroll
    for (int c = 0; c < 2; ++c) {
      const int ko = c * 32 + l4 * 8;
#pragma unroll
      for (int m = 0; m < 4; ++m) {
        const int row = m * 16 + l15;
        const short8 ah = *reinterpret_cast<const short8*>(&sm.s1.Xh[cur][row][ko]);
        const short8 al = *reinterpret_cast<const short8*>(&sm.s1.Xl[cur][row][ko]);
        accm[m] = __builtin_amdgcn_mfma_f32_16x16x32_bf16(ah, bhc[c], accm[m], 0, 0, 0);
        accm[m] = __builtin_amdgcn_mfma_f32_16x16x32_bf16(al, bhc[c], accm[m], 0, 0, 0);
        accm[m] = __builtin_amdgcn_mfma_f32_16x16x32_bf16(ah, blc[c], accm[m], 0, 0, 0);
        accr[m] = __builtin_amdgcn_mfma_f32_16x16x32_bf16(ah, brc[c], accr[m], 0, 0, 0);
      }
    }

    if (kt < 15) wrX(cur ^ 1, xa0, xa1);   // splitbf + ds_write after compute
    __syncthreads();

    // roll B double-buffer (SSA-renamed under full unroll)
#pragma unroll
    for (int c = 0; c < 2; ++c) { bhc[c] = bhn[c]; blc[c] = bln[c]; brc[c] = brn[c]; }
  }

  // prefetch all 12 W2 B-fragments; they land during the GELU VALU phase
  short8 b2h[4], b2l[4], b2r[4];
#pragma unroll
  for (int c2 = 0; c2 < 4; ++c2) {
    const size_t boff = (size_t)(((tn * 4 + c2) * 64 + lane) * 8);
    b2h[c2] = *reinterpret_cast<const short8*>(W2h + boff);
    b2l[c2] = *reinterpret_cast<const short8*>(W2l + boff);
    b2r[c2] = *reinterpret_cast<const short8*>(W2r + boff);
  }

  // bias + exact GELU -> H (m: hi/lo split, r: bf16)   [overlays s1 -> barrier above]
  const int n = tn * 16 + l15;
  {
    const float b1m = B1[n];
    const float b1rr = rB1[n];
#pragma unroll
    for (int m = 0; m < 4; ++m)
#pragma unroll
      for (int r = 0; r < 4; ++r) {
        const int row = m * 16 + l4 * 4 + r;
        const float v = accm[m][r] + b1m;
        const float ev = erff(v / 1.41421356237309515f);
        const float g = 0.5f * v * (ev + 1.0f);
        uint16_t gh, gl;
        splitbf(g, gh, gl);
        sm.s2.Hh[row][n] = gh;
        sm.s2.Hl[row][n] = gl;
        const float vr = accr[m][r] + b1rr;
        const float gr = 0.5f * vr * (1.0f + erff(vr * 0.70710678118654752f));
        sm.s2.Hr[row][n] = f2bf(gr);
      }
  }
  __syncthreads();

  // GEMM2 (K=128): m 3-term split + r single; W2 fragments already in regs
  f32x4 acc2m[4], acc2r[4];
#pragma unroll
  for (int m = 0; m < 4; ++m) { acc2m[m] = 0.0f; acc2r[m] = 0.0f; }

#pragma unroll
  for (int c2 = 0; c2 < 4; ++c2) {
    const int ko = c2 * 32 + l4 * 8;
#pragma unroll
    for (int m = 0; m < 4; ++m) {
      const int row = m * 16 + l15;
      const short8 ah = *reinterpret_cast<const short8*>(&sm.s2.Hh[row][ko]);
      const short8 al = *reinterpret_cast<const short8*>(&sm.s2.Hl[row][ko]);
      const short8 ar = *reinterpret_cast<const short8*>(&sm.s2.Hr[row][ko]);
      acc2m[m] = __builtin_amdgcn_mfma_f32_16x16x32_bf16(ah, b2h[c2], acc2m[m], 0, 0, 0);
      acc2m[m] = __builtin_amdgcn_mfma_f32_16x16x32_bf16(al, b2h[c2], acc2m[m], 0, 0, 0);
      acc2m[m] = __builtin_amdgcn_mfma_f32_16x16x32_bf16(ah, b2l[c2], acc2m[m], 0, 0, 0);
      acc2r[m] = __builtin_amdgcn_mfma_f32_16x16x32_bf16(ar, b2r[c2], acc2r[m], 0, 0, 0);
    }
  }

  // epilogue r: Pi, K, R (overwrite acc2r with K for the aggregate phase)
  {
    const float b2 = rB2[n];
    const float piv = PiArr[n];
#pragma unroll
    for (int m = 0; m < 4; ++m)
#pragma unroll
      for (int r = 0; r < 4; ++r) {
        const int token = tok0 + m * 16 + l4 * 4 + r;
        float lr = acc2r[m][r] + b2;
        lr = fminf(fmaxf(lr, -5.0f), 5.0f);
        const float R = expf(lr);
        const float K = piv / fmaxf(piv + R, 1e-8f);
        const size_t off = (size_t)token * CCH + n;
        out1[off] = piv;
        out2[off] = K;
        out3[off] = R;
        acc2r[m][r] = K;
      }
  }

  // epilogue m: nu via direct 2*pi wrap (boundary cases flagged for exact refine)
  {
    const float b2 = B2[n];
#pragma unroll
    for (int m = 0; m < 4; ++m)
#pragma unroll
      for (int r = 0; r < 4; ++r) {
        const int token = tok0 + m * 16 + l4 * 4 + r;
        const float mz = acc2m[m][r] + b2;
        const float z = 3.14159265358979323846f * tanhf(mz);
        const float d = z - theta[(size_t)token * CCH + n];
        const float wr = d - 6.2831853071795864769f * rintf(d * 0.15915494309189533577f);
        if (3.14159265358979323846f - fabsf(wr) < 3e-4f) {
          unsigned int p = atomicAdd(cnt, 1u);
          if (p < LIST_CAP) list[p] = (unsigned int)(token * CCH + n);
        }
        out0[(size_t)token * CCH + n] = wr;
        acc2m[m][r] = wr;
      }
  }

  // chunk aggregates: per (ch, m, l4) 4-token r-chain, then ordered compose
  __syncthreads();   // all H reads done; safe to reuse union as s3
#pragma unroll
  for (int m = 0; m < 4; ++m) {
    float A = 1.0f, U = 0.0f;
#pragma unroll
    for (int r = 0; r < 4; ++r) {
      const float k = acc2r[m][r];
      const float v = acc2m[m][r];
      const float a = 1.0f - k;
      A *= a;
      U = fmaf(a, U, k * v);
    }
    sm.s3.Agg[m][l4][n] = make_float2(A, U);
  }
  __syncthreads();
  if (tid < 128) {
    const int ch = tid;
    float A = 1.0f, U = 0.0f;
#pragma unroll
    for (int g = 0; g < 16; ++g) {
      const float2 au = sm.s3.Agg[g >> 2][g & 3][ch];
      U = fmaf(au.x, U, au.y);
      A *= au.x;
    }
    AggA[blockIdx.x * CCH + ch] = A;
    AggU[blockIdx.x * CCH + ch] = U;
  }
}

// ---------------- refine_nu: exact f32 sequential-chain recompute of flagged elems ----------------
__global__ __launch_bounds__(128) void refine_nu(
    const float* __restrict__ X, const float* __restrict__ theta,
    const float* __restrict__ W1, const float* __restrict__ B1,
    const float* __restrict__ W2, const float* __restrict__ B2,
    const unsigned int* __restrict__ cnt, const unsigned int* __restrict__ list,
    float* __restrict__ out0)
{
  __shared__ float h[128];
  const int j = threadIdx.x;
  const unsigned int n = min(cnt[0], LIST_CAP);
  for (unsigned int e = blockIdx.x; e < n; e += gridDim.x) {
    const unsigned int idx = list[e];
    const int tok = (int)(idx >> 7), ch = (int)(idx & 127);
    const float* xr = X + (size_t)tok * DIN;
    float acc = 0.0f;
    for (int k = 0; k < DIN; ++k)
      acc = fmaf(xr[k], W1[(size_t)k * CCH + j], acc);
    const float v = acc + B1[j];
    const float ev = erff(v / 1.41421356237309515f);
    h[j] = 0.5f * v * (ev + 1.0f);
    __syncthreads();
    if (j == 0) {
      float a2 = 0.0f;
      for (int k = 0; k < CCH; ++k)
        a2 = fmaf(h[k], W2[(size_t)k * CCH + ch], a2);
      const float mz = a2 + B2[ch];
      const float z = 3.14159265358979323846f * tanhf(mz);
      const float d = z - theta[(size_t)tok * CCH + ch];
      out0[(size_t)tok * CCH + ch] = atan2f(sinf(d), cosf(d));
    }
    __syncthreads();
  }
}

// ---------------- refine_agg: recompute chunk aggregates touched by refine_nu ----------------
__global__ __launch_bounds__(64) void refine_agg(
    const float* __restrict__ Kk, const float* __restrict__ nu,
    const unsigned int* __restrict__ cnt, const unsigned int* __restrict__ list,
    float* __restrict__ AggA, float* __restrict__ AggU)
{
  __shared__ float av[64], uv[64];
  const int i = threadIdx.x;
  const unsigned int n = min(cnt[0], LIST_CAP);
  for (unsigned int e = blockIdx.x; e < n; e += gridDim.x) {
    const unsigned int idx = list[e];
    const int ch = (int)(idx & 127);
    const int blk = (int)(idx >> 13);          // tok >> 6
    const size_t off = (size_t)(blk * 64 + i) * CCH + ch;
    const float k = Kk[off];
    const float v = nu[off];
    av[i] = 1.0f - k;
    uv[i] = k * v;
    __syncthreads();
    if (i == 0) {
      float A = 1.0f, U = 0.0f;
      for (int g = 0; g < 64; ++g) {
        U = fmaf(av[g], U, uv[g]);
        A *= av[g];
      }
      AggA[blk * CCH + ch] = A;
      AggU[blk * CCH + ch] = U;
    }
    __syncthreads();
  }
}

// ---------------- pass2: wave-parallel affine scan over 64 chunks ----------------
__global__ __launch_bounds__(256) void scan_pass2(
    const float* __restrict__ AggA, const float* __restrict__ AggU,
    float* __restrict__ Carry)
{
  const int wid = blockIdx.x * 4 + (threadIdx.x >> 6);  // 0..1023: (b, ch)
  const int b = wid >> 7, ch = wid & 127;
  const int g = threadIdx.x & 63;                        // chunk index
  const size_t idx = (size_t)(b * 64 + g) * CCH + ch;
  float A = AggA[idx];
  float U = AggU[idx];
#pragma unroll
  for (int s = 1; s < 64; s <<= 1) {
    const float pA = __shfl_up(A, s);
    const float pU = __shfl_up(U, s);
    if (g >= s) {
      U = fmaf(A, pU, U);
      A = A * pA;
    }
  }
  float cU = __shfl_up(U, 1);
  if (g == 0) cU = 0.0f;
  Carry[idx] = cU;
}

// ---------------- pass3: apply (K/nu LDS-staged; serial chain runs from LDS) ----------------
__global__ __launch_bounds__(128) void scan_pass3(
    const float* __restrict__ Kk, const float* __restrict__ theta,
    const float* __restrict__ Carry, float* __restrict__ out0)
{
  __shared__ float kb[64 * CCH];
  __shared__ float vb[64 * CCH];
  const int c = threadIdx.x;
  const int blk = blockIdx.x;
  const size_t base = (size_t)blk * 64 * CCH;
  // parallel stage: 8192 floats per array = 2048 float4; 128 threads x 16 each
#pragma unroll
  for (int i = 0; i < 16; ++i) {
    const int e = i * 128 + c;
    reinterpret_cast<float4*>(kb)[e] = reinterpret_cast<const float4*>(Kk + base)[e];
    reinterpret_cast<float4*>(vb)[e] = reinterpret_cast<const float4*>(out0 + base)[e];
  }
  __syncthreads();
  float d = Carry[blk * CCH + c];
#pragma unroll 8
  for (int i = 0; i < 64; ++i) {
    const float k = kb[i * CCH + c];
    const float v = vb[i * CCH + c];
    d = fmaf(1.0f - k, d, k * v);
    const size_t off = base + (size_t)i * CCH + c;
    out0[off] = theta[off] + d;
  }
}

extern "C" void kernel_launch(void* const* d_in, const int* in_sizes, int n_in,
                              void* d_out, int out_size, void* d_ws, size_t ws_size,
                              hipStream_t stream) {
  const float* theta   = (const float*)d_in[0];
  const float* X       = (const float*)d_in[1];
  const float* logQ    = (const float*)d_in[2];
  const float* logRavg = (const float*)d_in[3];
  const float* r_w1    = (const float*)d_in[4];
  const float* r_b1    = (const float*)d_in[5];
  const float* r_w2    = (const float*)d_in[6];
  const float* r_b2    = (const float*)d_in[7];
  const float* m_w1    = (const float*)d_in[8];
  const float* m_b1    = (const float*)d_in[9];
  const float* m_w2    = (const float*)d_in[10];
  const float* m_b2    = (const float*)d_in[11];

  float* out0 = (float*)d_out;             // theta + d (nu scratch first)
  float* out1 = out0 + 4194304;            // Pi
  float* out2 = out0 + 2 * 4194304;        // K
  float* out3 = out0 + 3 * 4194304;        // R

  char* ws = (char*)d_ws;
  uint16_t* W1r  = (uint16_t*)(ws);                  // 262144 B
  uint16_t* W2r  = (uint16_t*)(ws + 262144);         // 32768 B
  float* PiArr   = (float*)(ws + 295936);            // 512 B
  float* AggA    = (float*)(ws + 296448);            // 262144 B
  float* AggU    = (float*)(ws + 558592);            // 262144 B
  float* Carry   = (float*)(ws + 820736);            // 262144 B
  unsigned int* cnt  = (unsigned int*)(ws + 1082880);   // 256 B slot
  unsigned int* list = (unsigned int*)(ws + 1083136);   // 1048576 B
  uint16_t* W1mh = (uint16_t*)(ws + 2131712);        // 262144 B
  uint16_t* W1ml = (uint16_t*)(ws + 2393856);        // 262144 B
  uint16_t* W2mh = (uint16_t*)(ws + 2656000);        // 32768 B
  uint16_t* W2ml = (uint16_t*)(ws + 2688768);        // 32768 B

  prep_kernel<<<1153, 256, 0, stream>>>(r_w1, r_w2, m_w1, m_w2, logQ, logRavg,
                                        W1r, W2r, W1mh, W1ml, W2mh, W2ml,
                                        PiArr, cnt);
  fused_all<<<512, 512, 0, stream>>>(X, theta, W1r, W2r, W1mh, W1ml, W2mh, W2ml,
                                     r_b1, r_b2, m_b1, m_b2, PiArr,
                                     out0, out1, out2, out3, AggA, AggU, cnt, list);
  refine_nu<<<1024, 128, 0, stream>>>(X, theta, m_w1, m_b1, m_w2, m_b2,
                                      cnt, list, out0);
  refine_agg<<<1024, 64, 0, stream>>>(out2, out0, cnt, list, AggA, AggU);
  scan_pass2<<<256, 256, 0, stream>>>(AggA, AggU, Carry);
  scan_pass3<<<512, 128, 0, stream>>>(out2, theta, Carry, out0);
}